// Round 2
// baseline (4830.555 us; speedup 1.0000x reference)
//
#include <hip/hip_runtime.h>
#include <math.h>

#define IMG_H 256
#define IMG_W 256
#define IMG_SZ (IMG_H * IMG_W)
#define NP 49      /* C*p*p patch vector length */
#define HP 250     /* H - p + 1 */
#define NB 4096    /* groups per image = 64*64 */
#define NCAND 1369 /* 37*37 */
#define VRAD 18
#define CENTER (VRAD * 37 + VRAD)
#define NIMG 2

// Map aligned-patch coordinates (253x253, after align_corners with s=4 on a
// 250x250 grid) to original patch coordinates. Returns false for inf slots.
__device__ __forceinline__ bool align_map(int r, int c, int& ro, int& co) {
    if (r < 0 || r > 252 || c < 0 || c > 252) return false;
    if (r == 252) {
        if (c == 252) { ro = 249; co = 249; return true; }
        if (c <= 248 && (c & 3) == 0) { ro = 249; co = c; return true; }
        return false;
    }
    if (c == 252) {
        if (r <= 248 && (r & 3) == 0) { ro = r; co = 249; return true; }
        return false;
    }
    if (r >= 250 || c >= 250) return false;
    if (r == 249) {
        if (c == 249) return false;
        if ((c & 3) == 0) return false;
        ro = 249; co = c; return true;
    }
    if (c == 249) {
        if ((r & 3) == 0) return false;
        ro = r; co = 249; return true;
    }
    ro = r; co = c; return true;
}

__global__ void zero_kernel(float* __restrict__ p, int total) {
    int i = blockIdx.x * blockDim.x + threadIdx.x;
    if (i < total) p[i] = 0.0f;
}

// acc holds interleaved (num, weight) pairs per pixel.
__global__ void div_kernel(const float* __restrict__ acc, float* __restrict__ out, int total) {
    int i = blockIdx.x * blockDim.x + threadIdx.x;
    if (i < total) out[i] = acc[2 * i] / acc[2 * i + 1];
}

// One wave per reference patch. Search window staged in LDS; selection via
// barrier-free shfl butterfly over per-lane local minima + owner-lane rescan.
template <int M>
__global__ __launch_bounds__(64) void bm_kernel(const float* __restrict__ img,
                                                int* __restrict__ idx_out) {
    __shared__ float win[43 * 43];
    __shared__ float refp[NP];
    __shared__ float dist[NCAND];
    const int ll = blockIdx.x, kk = blockIdx.y, n = blockIdx.z;
    const float* im = img + (size_t)n * IMG_SZ;
    const int t = threadIdx.x;
    const int rr = (kk < 63) ? 4 * kk : 249;
    const int cc = (ll < 63) ? 4 * ll : 249;
    const int ar0 = 4 * kk, ac0 = 4 * ll;
    const int row0 = max(0, ar0 - VRAD), col0 = max(0, ac0 - VRAD);
    const int row1 = min(IMG_H - 1, ar0 + VRAD + 6), col1 = min(IMG_W - 1, ac0 + VRAD + 6);
    const int nr = row1 - row0 + 1, nc = col1 - col0 + 1;
    for (int e = t; e < nr * nc; e += 64) {
        int r = e / nc, c = e % nc;
        win[r * 43 + c] = im[(row0 + r) * IMG_W + col0 + c];
    }
    if (t < NP) refp[t] = im[(rr + t / 7) * IMG_W + (cc + t % 7)];
    __syncthreads();
    for (int cand = t; cand < NCAND; cand += 64) {
        const int dr = cand / 37 - VRAD, dc = cand % 37 - VRAD;
        int ro, co;
        float d;
        if (align_map(ar0 + dr, ac0 + dc, ro, co)) {
            const float* base = win + (ro - row0) * 43 + (co - col0);
            float s = 0.f;
#pragma unroll
            for (int ki = 0; ki < 7; ++ki)
#pragma unroll
                for (int kj = 0; kj < 7; ++kj) {
                    float df = base[ki * 43 + kj] - refp[ki * 7 + kj] + 1e-6f;
                    s = fmaf(df, df, s);
                }
            d = sqrtf(s);
        } else {
            d = INFINITY;
        }
        dist[cand] = d;
    }
    __syncthreads();
    if (t == (CENTER & 63)) dist[CENTER] = -1.0f;  // center always wins sel 0
    __syncthreads();
    // per-lane local min over its strided bucket (ascending scan => ties keep low idx)
    float mv = INFINITY;
    int mi = NCAND;
    for (int c = t; c < NCAND; c += 64) {
        float v = dist[c];
        if (v < mv) { mv = v; mi = c; }
    }
    int* out = idx_out + (size_t)((n * 64 + kk) * 64 + ll) * M;
    for (int sel = 0; sel < M; ++sel) {
        float gv = mv;
        int gi = mi;
#pragma unroll
        for (int off = 32; off; off >>= 1) {
            float vv = __shfl_xor(gv, off);
            int ii = __shfl_xor(gi, off);
            if (vv < gv || (vv == gv && ii < gi)) { gv = vv; gi = ii; }
        }
        if (t == 0) {
            int dr = gi / 37 - VRAD, dc = gi % 37 - VRAD;
            out[sel] = min(rr + dr, 249) * HP + min(cc + dc, 249);
        }
        if ((gi & 63) == t) {  // owner extracts and rescans its bucket
            dist[gi] = INFINITY;
            mv = INFINITY;
            mi = NCAND;
            for (int c = t; c < NCAND; c += 64) {
                float v = dist[c];
                if (v < mv) { mv = v; mi = c; }
            }
        }
    }
}

// One wave per group. theta = I - c*A^-1 in BOTH rounds (A = G for round1,
// G + c*I for round2, c = n*sigma^2). Packed-lower Cholesky in LDS; solves
// fully unrolled in registers with broadcast L reads. Weights via theta
// symmetry (row norm == column norm, in-lane). X_hat = Y - c*(A^-1 Y).
template <int M, bool R2>
__global__ __launch_bounds__(64) void denoise_kernel(
    const float* __restrict__ y, const float* __restrict__ xsrc,
    const int* __restrict__ idx, const float* __restrict__ sigma_p,
    float* __restrict__ acc) {
    constexpr int TPK = M * (M + 1) / 2;
    __shared__ float Ys[M][NP];
    __shared__ float Xs[R2 ? M : 1][NP];
    __shared__ float Apk[TPK];
    __shared__ float rLds[M];
    __shared__ float wsh[M];
    __shared__ int gix[M];
    const int b = blockIdx.x, n = blockIdx.y;
    const int t = threadIdx.x;
    if (t < M) gix[t] = idx[(size_t)(n * NB + b) * M + t];
    __syncthreads();
    const float* im = y + (size_t)n * IMG_SZ;
    const float* xim = xsrc + (size_t)n * IMG_SZ;
    for (int e = t; e < M * NP; e += 64) {
        int i = e / NP, ch = e % NP;
        int p = gix[i];
        int off = (p / HP + ch / 7) * IMG_W + (p % HP + ch % 7);
        Ys[i][ch] = im[off];
        if (R2) Xs[i][ch] = xim[off];
    }
    __syncthreads();
    const float sg = sigma_p[0];
    const float cns = 49.f * sg * sg;
    // Gram, lower triangle packed: Apk[i*(i+1)/2 + j], i >= j
    for (int e = t; e < TPK; e += 64) {
        int i = (int)((sqrtf(8.f * e + 1.f) - 1.f) * 0.5f);
        while ((i + 1) * (i + 2) / 2 <= e) ++i;
        while (i * (i + 1) / 2 > e) --i;
        int j = e - i * (i + 1) / 2;
        const float* Pi = R2 ? Xs[i] : Ys[i];
        const float* Pj = R2 ? Xs[j] : Ys[j];
        float s = 0.f;
#pragma unroll
        for (int k = 0; k < NP; ++k) s = fmaf(Pi[k], Pj[k], s);
        Apk[e] = (R2 && i == j) ? s + cns : s;
    }
    __syncthreads();
    // Packed right-looking Cholesky, trailing update balanced over lanes
    for (int k = 0; k < M; ++k) {
        if (t == 0) {
            float d = sqrtf(Apk[k * (k + 1) / 2 + k]);
            Apk[k * (k + 1) / 2 + k] = d;
            rLds[k] = 1.f / d;
        }
        __syncthreads();
        if (t > k && t < M) Apk[t * (t + 1) / 2 + k] *= rLds[k];
        __syncthreads();
        const int rem = M - 1 - k;
        const int cnt = rem * (rem + 1) / 2;
        for (int e = t; e < cnt; e += 64) {
            int r = (int)((sqrtf(8.f * e + 1.f) - 1.f) * 0.5f);
            while ((r + 1) * (r + 2) / 2 <= e) ++r;
            while (r * (r + 1) / 2 > e) --r;
            int c2 = e - r * (r + 1) / 2;
            int i = k + 1 + r, j = k + 1 + c2;
            Apk[i * (i + 1) / 2 + j] =
                fmaf(-Apk[i * (i + 1) / 2 + k], Apk[j * (j + 1) / 2 + k], Apk[i * (i + 1) / 2 + j]);
        }
        __syncthreads();
    }
    // ph0: lane t solves identity column t -> weights (theta symmetric).
    // ph1: lane ch solves Y column ch -> X_hat and fused aggregation.
#pragma unroll 1
    for (int ph = 0; ph < 2; ++ph) {
        float bb[M];
        if (ph == 0) {
#pragma unroll
            for (int i = 0; i < M; ++i) bb[i] = (i == t) ? 1.f : 0.f;
        } else {
            const int ch = (t < NP) ? t : 0;
#pragma unroll
            for (int i = 0; i < M; ++i) bb[i] = Ys[i][ch];
        }
        // forward: L z = b (update form; all reg indices compile-time)
#pragma unroll
        for (int i = 0; i < M; ++i) {
            bb[i] *= rLds[i];
#pragma unroll
            for (int j = i + 1; j < M; ++j)
                bb[j] = fmaf(-Apk[j * (j + 1) / 2 + i], bb[i], bb[j]);
        }
        // backward: L^T x = z
#pragma unroll
        for (int i = M - 1; i >= 0; --i) {
            bb[i] *= rLds[i];
#pragma unroll
            for (int j = 0; j < i; ++j)
                bb[j] = fmaf(-Apk[i * (i + 1) / 2 + j], bb[i], bb[j]);
        }
        if (ph == 0) {
            if (t < M) {
                float s2 = 0.f;
#pragma unroll
                for (int i = 0; i < M; ++i) {
                    float th = ((i == t) ? 1.f : 0.f) - cns * bb[i];
                    s2 = fmaf(th, th, s2);
                }
                s2 = fminf(fmaxf(s2, 1.f / (float)M), 1.f);
                wsh[t] = 1.f / s2;
            }
        } else {
            if (t < NP) {
                float* aA = acc + (size_t)n * IMG_SZ * 2;
                const int ch = t;
#pragma unroll
                for (int i = 0; i < M; ++i) {
                    int p = gix[i];
                    int pix = (p / HP + ch / 7) * IMG_W + (p % HP + ch % 7);
                    float xv = Ys[i][ch] - cns * bb[i];
                    float wi = wsh[i];
                    atomicAdd(&aA[pix * 2], xv * wi);
                    atomicAdd(&aA[pix * 2 + 1], wi);
                }
            }
        }
        __syncthreads();
    }
}

extern "C" void kernel_launch(void* const* d_in, const int* in_sizes, int n_in,
                              void* d_out, int out_size, void* d_ws, size_t ws_size,
                              hipStream_t stream) {
    const float* y = (const float*)d_in[0];
    const float* sigma = (const float*)d_in[1];
    float* out = (float*)d_out;

    char* ws = (char*)d_ws;
    size_t off = 0;
    auto carve = [&](size_t bytes) {
        void* p = ws + off;
        off += (bytes + 255) & ~(size_t)255;
        return p;
    };
    int* idx1 = (int*)carve((size_t)NIMG * NB * 18 * sizeof(int));
    int* idx2 = (int*)carve((size_t)NIMG * NB * 55 * sizeof(int));
    float* acc = (float*)carve((size_t)NIMG * IMG_SZ * 2 * sizeof(float));
    float* den1 = (float*)carve((size_t)NIMG * IMG_SZ * sizeof(float));

    const int accTotal = NIMG * IMG_SZ * 2;
    const int imgTotal = NIMG * IMG_SZ;

    // Round 1: M1=18
    zero_kernel<<<(accTotal + 255) / 256, 256, 0, stream>>>(acc, accTotal);
    bm_kernel<18><<<dim3(64, 64, NIMG), 64, 0, stream>>>(y, idx1);
    denoise_kernel<18, false><<<dim3(NB, NIMG), 64, 0, stream>>>(y, y, idx1, sigma, acc);
    div_kernel<<<(imgTotal + 255) / 256, 256, 0, stream>>>(acc, den1, imgTotal);

    // Round 2: M2=55
    zero_kernel<<<(accTotal + 255) / 256, 256, 0, stream>>>(acc, accTotal);
    bm_kernel<55><<<dim3(64, 64, NIMG), 64, 0, stream>>>(den1, idx2);
    denoise_kernel<55, true><<<dim3(NB, NIMG), 64, 0, stream>>>(y, den1, idx2, sigma, acc);
    div_kernel<<<(imgTotal + 255) / 256, 256, 0, stream>>>(acc, out, imgTotal);
}

// Round 3
// 1887.986 us; speedup vs baseline: 2.5586x; 2.5586x over previous
//
#include <hip/hip_runtime.h>
#include <math.h>

#define IMG_H 256
#define IMG_W 256
#define IMG_SZ (IMG_H * IMG_W)
#define NP 49      /* C*p*p patch vector length */
#define HP 250     /* H - p + 1 */
#define NB 4096    /* groups per image = 64*64 */
#define NCAND 1369 /* 37*37 */
#define VRAD 18
#define CENTER (VRAD * 37 + VRAD)
#define NIMG 2
#define YSTR 52    /* padded row stride: 52*4=208 bytes, 16B aligned */

__device__ __forceinline__ float f4el(const float4& v, int s) {
    return s == 0 ? v.x : s == 1 ? v.y : s == 2 ? v.z : v.w;
}

// Map aligned-patch coordinates (253x253, after align_corners with s=4 on a
// 250x250 grid) to original patch coordinates. Returns false for inf slots.
__device__ __forceinline__ bool align_map(int r, int c, int& ro, int& co) {
    if (r < 0 || r > 252 || c < 0 || c > 252) return false;
    if (r == 252) {
        if (c == 252) { ro = 249; co = 249; return true; }
        if (c <= 248 && (c & 3) == 0) { ro = 249; co = c; return true; }
        return false;
    }
    if (c == 252) {
        if (r <= 248 && (r & 3) == 0) { ro = r; co = 249; return true; }
        return false;
    }
    if (r >= 250 || c >= 250) return false;
    if (r == 249) {
        if (c == 249) return false;
        if ((c & 3) == 0) return false;
        ro = 249; co = c; return true;
    }
    if (c == 249) {
        if ((r & 3) == 0) return false;
        ro = r; co = 249; return true;
    }
    ro = r; co = c; return true;
}

__global__ void zero_kernel(float* __restrict__ p, int total) {
    int i = blockIdx.x * blockDim.x + threadIdx.x;
    if (i < total) p[i] = 0.0f;
}

// acc holds interleaved (num, weight) pairs per pixel.
__global__ void div_kernel(const float* __restrict__ acc, float* __restrict__ out, int total) {
    int i = blockIdx.x * blockDim.x + threadIdx.x;
    if (i < total) out[i] = acc[2 * i] / acc[2 * i + 1];
}

// One wave per reference patch. Search window staged in LDS; selection via
// barrier-free shfl butterfly over per-lane top-2 caches (rescan only on
// cache exhaustion).
template <int M>
__global__ __launch_bounds__(64) void bm_kernel(const float* __restrict__ img,
                                                int* __restrict__ idx_out) {
    __shared__ float win[43 * 43];
    __shared__ float refp[NP];
    __shared__ float dist[NCAND];
    const int ll = blockIdx.x, kk = blockIdx.y, n = blockIdx.z;
    const float* im = img + (size_t)n * IMG_SZ;
    const int t = threadIdx.x;
    const int rr = (kk < 63) ? 4 * kk : 249;
    const int cc = (ll < 63) ? 4 * ll : 249;
    const int ar0 = 4 * kk, ac0 = 4 * ll;
    const int row0 = max(0, ar0 - VRAD), col0 = max(0, ac0 - VRAD);
    const int row1 = min(IMG_H - 1, ar0 + VRAD + 6), col1 = min(IMG_W - 1, ac0 + VRAD + 6);
    const int nr = row1 - row0 + 1, nc = col1 - col0 + 1;
    for (int e = t; e < nr * nc; e += 64) {
        int r = e / nc, c = e % nc;
        win[r * 43 + c] = im[(row0 + r) * IMG_W + col0 + c];
    }
    if (t < NP) refp[t] = im[(rr + t / 7) * IMG_W + (cc + t % 7)];
    __syncthreads();
    for (int cand = t; cand < NCAND; cand += 64) {
        const int dr = cand / 37 - VRAD, dc = cand % 37 - VRAD;
        int ro, co;
        float d;
        if (align_map(ar0 + dr, ac0 + dc, ro, co)) {
            const float* base = win + (ro - row0) * 43 + (co - col0);
            float s = 0.f;
#pragma unroll
            for (int ki = 0; ki < 7; ++ki)
#pragma unroll
                for (int kj = 0; kj < 7; ++kj) {
                    float df = base[ki * 43 + kj] - refp[ki * 7 + kj] + 1e-6f;
                    s = fmaf(df, df, s);
                }
            d = sqrtf(s);
        } else {
            d = INFINITY;
        }
        dist[cand] = d;
    }
    __syncthreads();
    if (t == (CENTER & 63)) dist[CENTER] = -1.0f;  // center always wins sel 0
    __syncthreads();
    // per-lane top-2 over the strided bucket (ascending scan => ties keep low idx)
    float v1 = INFINITY, v2 = INFINITY;
    int i1 = NCAND, i2 = NCAND;
    for (int c = t; c < NCAND; c += 64) {
        float v = dist[c];
        if (v < v1) { v2 = v1; i2 = i1; v1 = v; i1 = c; }
        else if (v < v2) { v2 = v; i2 = c; }
    }
    int* out = idx_out + (size_t)((n * 64 + kk) * 64 + ll) * M;
    for (int sel = 0; sel < M; ++sel) {
        float gv = v1;
        int gi = i1;
#pragma unroll
        for (int off = 32; off; off >>= 1) {
            float vv = __shfl_xor(gv, off);
            int ii = __shfl_xor(gi, off);
            if (vv < gv || (vv == gv && ii < gi)) { gv = vv; gi = ii; }
        }
        if (t == 0) {
            int dr = gi / 37 - VRAD, dc = gi % 37 - VRAD;
            out[sel] = min(rr + dr, 249) * HP + min(cc + dc, 249);
        }
        if ((gi & 63) == t) {  // owner pops its cache; rescan only if exhausted
            dist[gi] = INFINITY;
            v1 = v2; i1 = i2; v2 = INFINITY; i2 = NCAND;
            if (i1 == NCAND) {
                for (int c = t; c < NCAND; c += 64) {
                    float v = dist[c];
                    if (v < v1) { v2 = v1; i2 = i1; v1 = v; i1 = c; }
                    else if (v < v2) { v2 = v; i2 = c; }
                }
            }
        }
    }
}

// Two waves (128 threads) per group. theta = I - c*A^-1 in BOTH rounds
// (A = G round1, G + c*I round2, c = n*sigma^2). Cholesky via unscaled d^2
// updates (1 barrier/step, fixed slot ownership), then scale+transpose into
// row-major AND col-major packed L. Solves: wave0 lanes own identity columns
// (-> weights), wave1 lanes own Y columns (-> X_hat); L read as aligned
// broadcast float4 with compile-time slot masks; bb[M] fully register-resident.
template <int M, bool R2>
__global__ __launch_bounds__(128, 2) void denoise_kernel(
    const float* __restrict__ y, const float* __restrict__ xsrc,
    const int* __restrict__ idx, const float* __restrict__ sigma_p,
    float* __restrict__ acc) {
    constexpr int TPK = M * (M + 1) / 2;
    constexpr int NS = (TPK + 127) / 128;
    __shared__ __align__(16) float Ys[M][YSTR];
    __shared__ __align__(16) float Xs[R2 ? M : 1][YSTR];
    __shared__ __align__(16) float Lr[TPK + 4];  // row-major packed (+overread pad)
    __shared__ __align__(16) float Lc[TPK + 4];  // col-major packed
    __shared__ float rdiag[M];
    __shared__ float invD[M];
    __shared__ float wsh[M];
    __shared__ int gix[M];
    const int b = blockIdx.x, n = blockIdx.y;
    const int t = threadIdx.x;
    if (t < M) gix[t] = idx[(size_t)(n * NB + b) * M + t];
    __syncthreads();
    const float* im = y + (size_t)n * IMG_SZ;
    const float* xim = xsrc + (size_t)n * IMG_SZ;
    for (int e = t; e < M * NP; e += 128) {
        int i = e / NP, ch = e % NP;
        int p = gix[i];
        int off = (p / HP + ch / 7) * IMG_W + (p % HP + ch % 7);
        Ys[i][ch] = im[off];
        if (R2) Xs[i][ch] = xim[off];
    }
    __syncthreads();
    const float sg = sigma_p[0];
    const float cns = 49.f * sg * sg;
    // --- fixed slot ownership: decode (i,j) for entries t, t+128, ... ---
    int si[NS], sj[NS], tj[NS];
#pragma unroll
    for (int s = 0; s < NS; ++s) {
        int e = t + 128 * s;
        if (e < TPK) {
            int i = (int)((sqrtf(8.f * e + 1.f) - 1.f) * 0.5f);
            while ((i + 1) * (i + 2) / 2 <= e) ++i;
            while (i * (i + 1) / 2 > e) --i;
            si[s] = i;
            sj[s] = e - i * (i + 1) / 2;
            tj[s] = sj[s] * (sj[s] + 1) / 2;
        } else {
            si[s] = -1; sj[s] = -1; tj[s] = 0;
        }
    }
    // --- Gram into Lr (packed lower) ---
#pragma unroll
    for (int s = 0; s < NS; ++s) {
        if (si[s] >= 0) {
            const float* Pi = R2 ? Xs[si[s]] : Ys[si[s]];
            const float* Pj = R2 ? Xs[sj[s]] : Ys[sj[s]];
            float sum = 0.f;
#pragma unroll
            for (int q = 0; q < 12; ++q) {
                float4 a = *(const float4*)(Pi + 4 * q);
                float4 c4 = *(const float4*)(Pj + 4 * q);
                sum = fmaf(a.x, c4.x, sum);
                sum = fmaf(a.y, c4.y, sum);
                sum = fmaf(a.z, c4.z, sum);
                sum = fmaf(a.w, c4.w, sum);
            }
            sum = fmaf(Pi[48], Pj[48], sum);
            if (R2 && si[s] == sj[s]) sum += cns;
            Lr[t + 128 * s] = sum;
        }
    }
    __syncthreads();
    if (t == 0) {  // owner of entry (0,0)
        float d = Lr[0];
        invD[0] = 1.f / d;
        rdiag[0] = 1.f / sqrtf(d);
    }
    __syncthreads();
    // --- Cholesky, unscaled update form: raw[i][j] -= raw[i][k]*raw[j][k]/D_k ---
    for (int k = 0; k < M - 1; ++k) {
        float ivd = invD[k];
#pragma unroll
        for (int s = 0; s < NS; ++s) {
            if (si[s] > k && sj[s] > k) {
                int e = t + 128 * s;
                float lik = Lr[e - sj[s] + k];  // tri(si)+k = e - sj + k
                float ljk = Lr[tj[s] + k];
                Lr[e] = fmaf(-(lik * ivd), ljk, Lr[e]);
            }
        }
#pragma unroll
        for (int s = 0; s < NS; ++s) {
            if (si[s] == k + 1 && sj[s] == k + 1) {
                float d = Lr[t + 128 * s];
                invD[k + 1] = 1.f / d;
                rdiag[k + 1] = 1.f / sqrtf(d);
            }
        }
        __syncthreads();
    }
    // --- scale raw -> L; write row-major (in place) and col-major copies ---
#pragma unroll
    for (int s = 0; s < NS; ++s) {
        if (si[s] >= 0) {
            int i = si[s], j = sj[s];
            float v = Lr[t + 128 * s] * rdiag[j];
            Lr[t + 128 * s] = v;
            Lc[j * M - (j * (j - 1)) / 2 + (i - j)] = v;
        }
    }
    __syncthreads();
    // --- solves: wave0 identity columns, wave1 Y columns ---
    const bool isId = (t < M);
    const bool isY = (t >= 64 && t < 64 + NP);
    const int ch = t - 64;
    float bb[M];
    if (isY) {
#pragma unroll
        for (int i = 0; i < M; ++i) bb[i] = Ys[i][ch];
    } else {
#pragma unroll
        for (int i = 0; i < M; ++i) bb[i] = (i == t) ? 1.f : 0.f;
    }
    // forward: L z = b, walking packed col-major columns as aligned float4
#pragma unroll
    for (int i = 0; i < M; ++i) {
        float bbi = bb[i] * rdiag[i];
        bb[i] = bbi;
        const int cb = i * M - (i * (i - 1)) / 2;  // packed offset of (i,i)
#pragma unroll
        for (int q = (cb + 1) & ~3; q <= cb + (M - 1 - i); q += 4) {
            float4 L4 = *(const float4*)&Lc[q];
#pragma unroll
            for (int s2 = 0; s2 < 4; ++s2) {
                int j = i + (q + s2 - cb);
                if (j > i && j < M) bb[j] = fmaf(-f4el(L4, s2), bbi, bb[j]);
            }
        }
        if ((i & 1) == 1) asm volatile("" ::: "memory");  // cap load hoisting
    }
    // backward: L^T x = z, walking packed row-major rows as aligned float4
#pragma unroll
    for (int i = M - 1; i >= 0; --i) {
        float bbi = bb[i] * rdiag[i];
        bb[i] = bbi;
        const int rb = (i * (i + 1)) / 2;  // packed offset of (i,0)
#pragma unroll
        for (int q = rb & ~3; q < rb + i; q += 4) {
            float4 L4 = *(const float4*)&Lr[q];
#pragma unroll
            for (int s2 = 0; s2 < 4; ++s2) {
                int j = q + s2 - rb;
                if (j >= 0 && j < i) bb[j] = fmaf(-f4el(L4, s2), bbi, bb[j]);
            }
        }
        if ((i & 1) == 0) asm volatile("" ::: "memory");
    }
    // --- epilogue: weights from identity columns (theta symmetric), X_hat in place ---
    if (isId) {
        float s2 = 0.f;
#pragma unroll
        for (int i = 0; i < M; ++i) {
            float th = ((i == t) ? 1.f : 0.f) - cns * bb[i];
            s2 = fmaf(th, th, s2);
        }
        s2 = fminf(fmaxf(s2, 1.f / (float)M), 1.f);
        wsh[t] = 1.f / s2;
    }
    if (isY) {
#pragma unroll
        for (int i = 0; i < M; ++i) Ys[i][ch] = fmaf(-cns, bb[i], Ys[i][ch]);
    }
    __syncthreads();
    float* aA = acc + (size_t)n * IMG_SZ * 2;
    for (int e = t; e < M * NP; e += 128) {
        int i = e / NP, c2 = e % NP;
        int p = gix[i];
        int pix = (p / HP + c2 / 7) * IMG_W + (p % HP + c2 % 7);
        float wi = wsh[i];
        atomicAdd(&aA[pix * 2], Ys[i][c2] * wi);
        atomicAdd(&aA[pix * 2 + 1], wi);
    }
}

extern "C" void kernel_launch(void* const* d_in, const int* in_sizes, int n_in,
                              void* d_out, int out_size, void* d_ws, size_t ws_size,
                              hipStream_t stream) {
    const float* y = (const float*)d_in[0];
    const float* sigma = (const float*)d_in[1];
    float* out = (float*)d_out;

    char* ws = (char*)d_ws;
    size_t off = 0;
    auto carve = [&](size_t bytes) {
        void* p = ws + off;
        off += (bytes + 255) & ~(size_t)255;
        return p;
    };
    int* idx1 = (int*)carve((size_t)NIMG * NB * 18 * sizeof(int));
    int* idx2 = (int*)carve((size_t)NIMG * NB * 55 * sizeof(int));
    float* acc = (float*)carve((size_t)NIMG * IMG_SZ * 2 * sizeof(float));
    float* den1 = (float*)carve((size_t)NIMG * IMG_SZ * sizeof(float));

    const int accTotal = NIMG * IMG_SZ * 2;
    const int imgTotal = NIMG * IMG_SZ;

    // Round 1: M1=18
    zero_kernel<<<(accTotal + 255) / 256, 256, 0, stream>>>(acc, accTotal);
    bm_kernel<18><<<dim3(64, 64, NIMG), 64, 0, stream>>>(y, idx1);
    denoise_kernel<18, false><<<dim3(NB, NIMG), 128, 0, stream>>>(y, y, idx1, sigma, acc);
    div_kernel<<<(imgTotal + 255) / 256, 256, 0, stream>>>(acc, den1, imgTotal);

    // Round 2: M2=55
    zero_kernel<<<(accTotal + 255) / 256, 256, 0, stream>>>(acc, accTotal);
    bm_kernel<55><<<dim3(64, 64, NIMG), 64, 0, stream>>>(den1, idx2);
    denoise_kernel<55, true><<<dim3(NB, NIMG), 128, 0, stream>>>(y, den1, idx2, sigma, acc);
    div_kernel<<<(imgTotal + 255) / 256, 256, 0, stream>>>(acc, out, imgTotal);
}

// Round 4
// 1505.009 us; speedup vs baseline: 3.2097x; 1.2545x over previous
//
#include <hip/hip_runtime.h>
#include <math.h>

#define IMG_H 256
#define IMG_W 256
#define IMG_SZ (IMG_H * IMG_W)
#define NP 49      /* C*p*p patch vector length */
#define HP 250     /* H - p + 1 */
#define NB 4096    /* groups per image = 64*64 */
#define NCAND 1369 /* 37*37 */
#define VRAD 18
#define CENTER (VRAD * 37 + VRAD)
#define NIMG 2
#define YSTR 52    /* padded Y row stride: 208B, 16B aligned */

// Map aligned-patch coordinates (253x253, after align_corners with s=4 on a
// 250x250 grid) to original patch coordinates. Returns false for inf slots.
__device__ __forceinline__ bool align_map(int r, int c, int& ro, int& co) {
    if (r < 0 || r > 252 || c < 0 || c > 252) return false;
    if (r == 252) {
        if (c == 252) { ro = 249; co = 249; return true; }
        if (c <= 248 && (c & 3) == 0) { ro = 249; co = c; return true; }
        return false;
    }
    if (c == 252) {
        if (r <= 248 && (r & 3) == 0) { ro = r; co = 249; return true; }
        return false;
    }
    if (r >= 250 || c >= 250) return false;
    if (r == 249) {
        if (c == 249) return false;
        if ((c & 3) == 0) return false;
        ro = 249; co = c; return true;
    }
    if (c == 249) {
        if ((r & 3) == 0) return false;
        ro = r; co = 249; return true;
    }
    ro = r; co = c; return true;
}

__global__ void zero_kernel(float* __restrict__ p, int total) {
    int i = blockIdx.x * blockDim.x + threadIdx.x;
    if (i < total) p[i] = 0.0f;
}

// acc holds interleaved (num, weight) pairs per pixel.
__global__ void div_kernel(const float* __restrict__ acc, float* __restrict__ out, int total) {
    int i = blockIdx.x * blockDim.x + threadIdx.x;
    if (i < total) out[i] = acc[2 * i] / acc[2 * i + 1];
}

// One wave per reference patch. Search window staged in LDS; selection via
// barrier-free shfl butterfly over per-lane top-2 caches (rescan only on
// cache exhaustion).
template <int M>
__global__ __launch_bounds__(64) void bm_kernel(const float* __restrict__ img,
                                                int* __restrict__ idx_out) {
    __shared__ float win[43 * 43];
    __shared__ float refp[NP];
    __shared__ float dist[NCAND];
    const int ll = blockIdx.x, kk = blockIdx.y, n = blockIdx.z;
    const float* im = img + (size_t)n * IMG_SZ;
    const int t = threadIdx.x;
    const int rr = (kk < 63) ? 4 * kk : 249;
    const int cc = (ll < 63) ? 4 * ll : 249;
    const int ar0 = 4 * kk, ac0 = 4 * ll;
    const int row0 = max(0, ar0 - VRAD), col0 = max(0, ac0 - VRAD);
    const int row1 = min(IMG_H - 1, ar0 + VRAD + 6), col1 = min(IMG_W - 1, ac0 + VRAD + 6);
    const int nr = row1 - row0 + 1, nc = col1 - col0 + 1;
    for (int e = t; e < nr * nc; e += 64) {
        int r = e / nc, c = e % nc;
        win[r * 43 + c] = im[(row0 + r) * IMG_W + col0 + c];
    }
    if (t < NP) refp[t] = im[(rr + t / 7) * IMG_W + (cc + t % 7)];
    __syncthreads();
    for (int cand = t; cand < NCAND; cand += 64) {
        const int dr = cand / 37 - VRAD, dc = cand % 37 - VRAD;
        int ro, co;
        float d;
        if (align_map(ar0 + dr, ac0 + dc, ro, co)) {
            const float* base = win + (ro - row0) * 43 + (co - col0);
            float s = 0.f;
#pragma unroll
            for (int ki = 0; ki < 7; ++ki)
#pragma unroll
                for (int kj = 0; kj < 7; ++kj) {
                    float df = base[ki * 43 + kj] - refp[ki * 7 + kj] + 1e-6f;
                    s = fmaf(df, df, s);
                }
            d = sqrtf(s);
        } else {
            d = INFINITY;
        }
        dist[cand] = d;
    }
    __syncthreads();
    if (t == (CENTER & 63)) dist[CENTER] = -1.0f;  // center always wins sel 0
    __syncthreads();
    // per-lane top-2 over the strided bucket (ascending scan => ties keep low idx)
    float v1 = INFINITY, v2 = INFINITY;
    int i1 = NCAND, i2 = NCAND;
    for (int c = t; c < NCAND; c += 64) {
        float v = dist[c];
        if (v < v1) { v2 = v1; i2 = i1; v1 = v; i1 = c; }
        else if (v < v2) { v2 = v; i2 = c; }
    }
    int* out = idx_out + (size_t)((n * 64 + kk) * 64 + ll) * M;
    for (int sel = 0; sel < M; ++sel) {
        float gv = v1;
        int gi = i1;
#pragma unroll
        for (int off = 32; off; off >>= 1) {
            float vv = __shfl_xor(gv, off);
            int ii = __shfl_xor(gi, off);
            if (vv < gv || (vv == gv && ii < gi)) { gv = vv; gi = ii; }
        }
        if (t == 0) {
            int dr = gi / 37 - VRAD, dc = gi % 37 - VRAD;
            out[sel] = min(rr + dr, 249) * HP + min(cc + dc, 249);
        }
        if ((gi & 63) == t) {  // owner pops its cache; rescan only if exhausted
            dist[gi] = INFINITY;
            v1 = v2; i1 = i2; v2 = INFINITY; i2 = NCAND;
            if (i1 == NCAND) {
                for (int c = t; c < NCAND; c += 64) {
                    float v = dist[c];
                    if (v < v1) { v2 = v1; i2 = i1; v1 = v; i1 = c; }
                    else if (v < v2) { v2 = v; i2 = c; }
                }
            }
        }
    }
}

// Two waves (128 threads) per group. theta = I - c*A^-1 in BOTH rounds
// (A = G round1, G + c*I round2, c = n*sigma^2). d^2-form Cholesky (1 barrier
// per column), padded L[PADM][PADM] overlaying the dead Xs region (Gram staged
// through registers). Solves: wave0 lanes own identity columns (-> weights),
// wave1 lanes own Y columns (-> X_hat); forward solve in 4-wide chunks, all
// L reads are wave-uniform aligned float4 broadcasts.
template <int M, bool R2>
__global__ __launch_bounds__(128, 2) void denoise_kernel(
    const float* __restrict__ y, const float* __restrict__ xsrc,
    const int* __restrict__ idx, const float* __restrict__ sigma_p,
    float* __restrict__ acc) {
    constexpr int PADM = (M + 3) & ~3;  // 56 for M=55, 20 for M=18
    constexpr int PD = PADM;            // L stride (floats); PD*4 % 16 == 0
    constexpr int TPK = M * (M + 1) / 2;
    constexpr int NS = (TPK + 127) / 128;
    __shared__ __align__(16) float Ys[M][YSTR];
    __shared__ __align__(16) float SB[PADM * PD];  // R2: Xs rows (stride PD) -> later L
    __shared__ float rdiag[PADM];
    __shared__ float wsh[M];
    __shared__ int gix[M];
    const int b = blockIdx.x, n = blockIdx.y;
    const int t = threadIdx.x;
    if (t < M) gix[t] = idx[(size_t)(n * NB + b) * M + t];
    __syncthreads();
    const float* im = y + (size_t)n * IMG_SZ;
    const float* xim = xsrc + (size_t)n * IMG_SZ;
    for (int e = t; e < M * YSTR; e += 128) {
        int i = e / YSTR, ch = e - i * YSTR;
        int p = gix[i];
        float v = 0.f, vx = 0.f;
        if (ch < NP) {
            int off = (p / HP + ch / 7) * IMG_W + (p % HP + ch % 7);
            v = im[off];
            if (R2) vx = xim[off];
        }
        Ys[i][ch] = v;
        if (R2) SB[i * PD + ch] = vx;  // cols [0,52); cols >=52 junk, never read
    }
    __syncthreads();
    const float sg = sigma_p[0];
    const float cns = 49.f * sg * sg;
    // --- slot decode (packed lower triangle, fixed ownership) ---
    int siR[NS], sjR[NS];
    float gsum[NS];
#pragma unroll
    for (int s = 0; s < NS; ++s) {
        int e = t + 128 * s;
        if (e < TPK) {
            int i = (int)((sqrtf(8.f * e + 1.f) - 1.f) * 0.5f);
            while ((i + 1) * (i + 2) / 2 <= e) ++i;
            while (i * (i + 1) / 2 > e) --i;
            siR[s] = i;
            sjR[s] = e - i * (i + 1) / 2;
        } else {
            siR[s] = -1;
            sjR[s] = 0;
        }
    }
    // --- Gram into registers (reads Ys or SB-as-Xs) ---
#pragma unroll
    for (int s = 0; s < NS; ++s) {
        float sum = 0.f;
        if (siR[s] >= 0) {
            const float* Pi = R2 ? &SB[siR[s] * PD] : &Ys[siR[s]][0];
            const float* Pj = R2 ? &SB[sjR[s] * PD] : &Ys[sjR[s]][0];
#pragma unroll
            for (int q = 0; q < 13; ++q) {
                float4 a = *(const float4*)(Pi + 4 * q);
                float4 c4 = *(const float4*)(Pj + 4 * q);
                sum = fmaf(a.x, c4.x, sum);
                sum = fmaf(a.y, c4.y, sum);
                sum = fmaf(a.z, c4.z, sum);
                sum = fmaf(a.w, c4.w, sum);
            }
            if (R2 && siR[s] == sjR[s]) sum += cns;
        }
        gsum[s] = sum;
    }
    __syncthreads();  // all Gram reads of SB complete before overlay
    // --- write A into padded L buffer; identity-fill padding rows ---
#pragma unroll
    for (int s = 0; s < NS; ++s)
        if (siR[s] >= 0) SB[siR[s] * PD + sjR[s]] = gsum[s];
    for (int e = t; e < (PADM - M) * PADM; e += 128) {
        int pr = M + e / PADM, pc = e % PADM;
        SB[pr * PD + pc] = (pr == pc) ? 1.f : 0.f;
    }
    __syncthreads();
    // --- d^2-form Cholesky: raw[i][j] -= raw[i][k]*raw[j][k]/D_k ---
#pragma unroll 1
    for (int k = 0; k < M - 1; ++k) {
        float ivd = 1.f / SB[k * PD + k];  // broadcast; all lanes compute
#pragma unroll
        for (int s = 0; s < NS; ++s) {
            if (siR[s] > k && sjR[s] > k) {
                float lik = SB[siR[s] * PD + k];
                float ljk = SB[sjR[s] * PD + k];
                float* pv = &SB[siR[s] * PD + sjR[s]];
                *pv = fmaf(-(lik * ivd), ljk, *pv);
            }
        }
        __syncthreads();
    }
    if (t < PADM) rdiag[t] = (t < M) ? 1.f / sqrtf(SB[t * PD + t]) : 1.f;
    __syncthreads();
    // --- scale raw -> L (L[i][j] = raw[i][j]/sqrt(D_j)) ---
#pragma unroll
    for (int s = 0; s < NS; ++s)
        if (siR[s] >= 0) SB[siR[s] * PD + sjR[s]] *= rdiag[sjR[s]];
    __syncthreads();
    // --- solves: wave0 identity columns, wave1 Y columns ---
    const bool isId = (t < M);
    const bool isY = (t >= 64 && t - 64 < NP);
    const int ch = t - 64;
    float bb[PADM];
    if (isY) {
#pragma unroll
        for (int i = 0; i < PADM; ++i) bb[i] = (i < M) ? Ys[i][ch] : 0.f;
    } else {
#pragma unroll
        for (int i = 0; i < PADM; ++i) bb[i] = (i == t) ? 1.f : 0.f;
    }
    // forward: L z = b, 4-wide chunks; all L loads wave-uniform broadcasts
#pragma unroll
    for (int c = 0; c < PADM / 4; ++c) {
        const int i0 = 4 * c;
        float L10 = SB[(i0 + 1) * PD + i0];
        float L20 = SB[(i0 + 2) * PD + i0], L21 = SB[(i0 + 2) * PD + i0 + 1];
        float L30 = SB[(i0 + 3) * PD + i0], L31 = SB[(i0 + 3) * PD + i0 + 1],
              L32 = SB[(i0 + 3) * PD + i0 + 2];
        float b0 = bb[i0] * rdiag[i0];
        float b1 = (bb[i0 + 1] - L10 * b0) * rdiag[i0 + 1];
        float b2 = (bb[i0 + 2] - L20 * b0 - L21 * b1) * rdiag[i0 + 2];
        float b3 = (bb[i0 + 3] - L30 * b0 - L31 * b1 - L32 * b2) * rdiag[i0 + 3];
        bb[i0] = b0; bb[i0 + 1] = b1; bb[i0 + 2] = b2; bb[i0 + 3] = b3;
#pragma unroll
        for (int j = i0 + 4; j < PADM; ++j) {
            float4 L4 = *(const float4*)&SB[j * PD + i0];
            bb[j] = fmaf(-L4.x, b0, fmaf(-L4.y, b1, fmaf(-L4.z, b2, fmaf(-L4.w, b3, bb[j]))));
        }
        asm volatile("" ::: "memory");  // cap load hoisting across chunks
    }
    // backward: L^T x = z, row sweeps as aligned float4 + compile-time tails
#pragma unroll
    for (int i = PADM - 1; i >= 0; --i) {
        float bbi = bb[i] * rdiag[i];
        bb[i] = bbi;
#pragma unroll
        for (int qb = 0; qb < i / 4; ++qb) {
            float4 L4 = *(const float4*)&SB[i * PD + 4 * qb];
            bb[4 * qb + 0] = fmaf(-L4.x, bbi, bb[4 * qb + 0]);
            bb[4 * qb + 1] = fmaf(-L4.y, bbi, bb[4 * qb + 1]);
            bb[4 * qb + 2] = fmaf(-L4.z, bbi, bb[4 * qb + 2]);
            bb[4 * qb + 3] = fmaf(-L4.w, bbi, bb[4 * qb + 3]);
        }
#pragma unroll
        for (int j = i & ~3; j < i; ++j)
            bb[j] = fmaf(-SB[i * PD + j], bbi, bb[j]);
        if ((i & 3) == 0) asm volatile("" ::: "memory");
    }
    // --- epilogue: weights (theta symmetric), X_hat in place, fused scatter ---
    if (isId) {
        float s2 = 0.f;
#pragma unroll
        for (int i = 0; i < M; ++i) {
            float th = ((i == t) ? 1.f : 0.f) - cns * bb[i];
            s2 = fmaf(th, th, s2);
        }
        s2 = fminf(fmaxf(s2, 1.f / (float)M), 1.f);
        wsh[t] = 1.f / s2;
    }
    if (isY) {
#pragma unroll
        for (int i = 0; i < M; ++i) Ys[i][ch] = fmaf(-cns, bb[i], Ys[i][ch]);
    }
    __syncthreads();
    float* aA = acc + (size_t)n * IMG_SZ * 2;
    for (int e = t; e < M * NP; e += 128) {
        int i = e / NP, c2 = e % NP;
        int p = gix[i];
        int pix = (p / HP + c2 / 7) * IMG_W + (p % HP + c2 % 7);
        float wi = wsh[i];
        atomicAdd(&aA[pix * 2], Ys[i][c2] * wi);
        atomicAdd(&aA[pix * 2 + 1], wi);
    }
}

extern "C" void kernel_launch(void* const* d_in, const int* in_sizes, int n_in,
                              void* d_out, int out_size, void* d_ws, size_t ws_size,
                              hipStream_t stream) {
    const float* y = (const float*)d_in[0];
    const float* sigma = (const float*)d_in[1];
    float* out = (float*)d_out;

    char* ws = (char*)d_ws;
    size_t off = 0;
    auto carve = [&](size_t bytes) {
        void* p = ws + off;
        off += (bytes + 255) & ~(size_t)255;
        return p;
    };
    int* idx1 = (int*)carve((size_t)NIMG * NB * 18 * sizeof(int));
    int* idx2 = (int*)carve((size_t)NIMG * NB * 55 * sizeof(int));
    float* acc = (float*)carve((size_t)NIMG * IMG_SZ * 2 * sizeof(float));
    float* den1 = (float*)carve((size_t)NIMG * IMG_SZ * sizeof(float));

    const int accTotal = NIMG * IMG_SZ * 2;
    const int imgTotal = NIMG * IMG_SZ;

    // Round 1: M1=18
    zero_kernel<<<(accTotal + 255) / 256, 256, 0, stream>>>(acc, accTotal);
    bm_kernel<18><<<dim3(64, 64, NIMG), 64, 0, stream>>>(y, idx1);
    denoise_kernel<18, false><<<dim3(NB, NIMG), 128, 0, stream>>>(y, y, idx1, sigma, acc);
    div_kernel<<<(imgTotal + 255) / 256, 256, 0, stream>>>(acc, den1, imgTotal);

    // Round 2: M2=55
    zero_kernel<<<(accTotal + 255) / 256, 256, 0, stream>>>(acc, accTotal);
    bm_kernel<55><<<dim3(64, 64, NIMG), 64, 0, stream>>>(den1, idx2);
    denoise_kernel<55, true><<<dim3(NB, NIMG), 128, 0, stream>>>(y, den1, idx2, sigma, acc);
    div_kernel<<<(imgTotal + 255) / 256, 256, 0, stream>>>(acc, out, imgTotal);
}

// Round 5
// 1452.090 us; speedup vs baseline: 3.3266x; 1.0364x over previous
//
#include <hip/hip_runtime.h>
#include <math.h>

#define IMG_H 256
#define IMG_W 256
#define IMG_SZ (IMG_H * IMG_W)
#define NP 49      /* C*p*p patch vector length */
#define HP 250     /* H - p + 1 */
#define NB 4096    /* groups per image = 64*64 */
#define NCAND 1369 /* 37*37 */
#define VRAD 18
#define CENTER (VRAD * 37 + VRAD)
#define NIMG 2
#define YSTR 52    /* Ys row stride: 208B (window-tiled, 16B aligned) */
#define SBSTR 60   /* SB row stride: 240B = 8x16B window tiling (b128 floor) */
#define WSTR 55    /* bm window stride: odd -> conflict-free */

// Map aligned-patch coordinates (253x253, after align_corners with s=4 on a
// 250x250 grid) to original patch coordinates. Returns false for inf slots.
__device__ __forceinline__ bool align_map(int r, int c, int& ro, int& co) {
    if (r < 0 || r > 252 || c < 0 || c > 252) return false;
    if (r == 252) {
        if (c == 252) { ro = 249; co = 249; return true; }
        if (c <= 248 && (c & 3) == 0) { ro = 249; co = c; return true; }
        return false;
    }
    if (c == 252) {
        if (r <= 248 && (r & 3) == 0) { ro = r; co = 249; return true; }
        return false;
    }
    if (r >= 250 || c >= 250) return false;
    if (r == 249) {
        if (c == 249) return false;
        if ((c & 3) == 0) return false;
        ro = 249; co = c; return true;
    }
    if (c == 249) {
        if ((r & 3) == 0) return false;
        ro = r; co = 249; return true;
    }
    ro = r; co = c; return true;
}

__global__ void zero_kernel(float* __restrict__ p, int total) {
    int i = blockIdx.x * blockDim.x + threadIdx.x;
    if (i < total) p[i] = 0.0f;
}

// acc holds interleaved (num, weight) pairs per pixel.
__global__ void div_kernel(const float* __restrict__ acc, float* __restrict__ out, int total) {
    int i = blockIdx.x * blockDim.x + threadIdx.x;
    if (i < total) out[i] = acc[2 * i] / acc[2 * i + 1];
}

// 4 reference patches per 256-thread block (one wave each), sharing one staged
// union window. refp in registers; center forced during fill; selection via
// barrier-free shfl butterfly over per-lane top-2 caches.
template <int M>
__global__ __launch_bounds__(256) void bm_kernel(const float* __restrict__ img,
                                                 int* __restrict__ idx_out) {
    __shared__ float win[43 * WSTR];
    __shared__ float dist[4][NCAND];
    const int llb = blockIdx.x, kk = blockIdx.y, n = blockIdx.z;
    const float* im = img + (size_t)n * IMG_SZ;
    const int t = threadIdx.x;
    const int w = t >> 6, lane = t & 63;
    const int ll = 4 * llb + w;
    const int rr = (kk < 63) ? 4 * kk : 249;
    const int cc = (ll < 63) ? 4 * ll : 249;
    const int ar0 = 4 * kk, ac0 = 4 * ll;
    const int acb = 16 * llb;
    const int row0 = max(0, ar0 - VRAD), col0 = max(0, acb - VRAD);
    const int row1 = min(IMG_H - 1, ar0 + VRAD + 6);
    const int col1 = min(IMG_W - 1, acb + 12 + VRAD + 6);
    const int nr = row1 - row0 + 1, nc = col1 - col0 + 1;
    for (int e = t; e < nr * nc; e += 256) {
        int r = e / nc, c = e % nc;
        win[r * WSTR + c] = im[(row0 + r) * IMG_W + col0 + c];
    }
    __syncthreads();
    float rf[NP];
    {
        const float* rb = &win[(rr - row0) * WSTR + (cc - col0)];
#pragma unroll
        for (int ki = 0; ki < 7; ++ki)
#pragma unroll
            for (int kj = 0; kj < 7; ++kj) rf[ki * 7 + kj] = rb[ki * WSTR + kj];
    }
    float* dw = dist[w];
    for (int cand = lane; cand < NCAND; cand += 64) {
        const int dr = cand / 37 - VRAD, dc = cand % 37 - VRAD;
        int ro, co;
        float d;
        if (align_map(ar0 + dr, ac0 + dc, ro, co)) {
            const float* base = &win[(ro - row0) * WSTR + (co - col0)];
            float s = 0.f;
#pragma unroll
            for (int ki = 0; ki < 7; ++ki)
#pragma unroll
                for (int kj = 0; kj < 7; ++kj) {
                    float df = base[ki * WSTR + kj] - rf[ki * 7 + kj] + 1e-6f;
                    s = fmaf(df, df, s);
                }
            d = sqrtf(s);
        } else {
            d = INFINITY;
        }
        if (cand == CENTER) d = -1.0f;  // center always wins sel 0
        dw[cand] = d;
    }
    __syncthreads();
    // per-lane top-2 over the strided bucket (ascending scan => ties keep low idx)
    float v1 = INFINITY, v2 = INFINITY;
    int i1 = NCAND, i2 = NCAND;
    for (int c = lane; c < NCAND; c += 64) {
        float v = dw[c];
        if (v < v1) { v2 = v1; i2 = i1; v1 = v; i1 = c; }
        else if (v < v2) { v2 = v; i2 = c; }
    }
    int* out = idx_out + (size_t)((n * 64 + kk) * 64 + ll) * M;
    for (int sel = 0; sel < M; ++sel) {
        float gv = v1;
        int gi = i1;
#pragma unroll
        for (int off = 32; off; off >>= 1) {
            float vv = __shfl_xor(gv, off);
            int ii = __shfl_xor(gi, off);
            if (vv < gv || (vv == gv && ii < gi)) { gv = vv; gi = ii; }
        }
        if (lane == 0) {
            int dr = gi / 37 - VRAD, dc = gi % 37 - VRAD;
            out[sel] = min(rr + dr, 249) * HP + min(cc + dc, 249);
        }
        if ((gi & 63) == lane) {  // owner pops its cache; rescan only if exhausted
            dw[gi] = INFINITY;
            v1 = v2; i1 = i2; v2 = INFINITY; i2 = NCAND;
            if (i1 == NCAND) {
                for (int c = lane; c < NCAND; c += 64) {
                    float v = dw[c];
                    if (v < v1) { v2 = v1; i2 = i1; v1 = v; i1 = c; }
                    else if (v < v2) { v2 = v; i2 = c; }
                }
            }
        }
    }
}

// 256 threads (4 waves) per group. theta = I - c*A^-1 in BOTH rounds
// (A = G round1, G + c*I round2, c = n*sigma^2). Gram + trailing Cholesky
// matrix held in REGISTERS (fixed slot ownership); per-column step touches
// only a ping-pong column buffer (conflict-free). L written once to SB
// (stride 60 = b128 window-tiling floor). Solves: 104 columns spread 26/wave;
// all L reads wave-uniform aligned float4 broadcasts.
template <int M, bool R2>
__global__ __launch_bounds__(256, 4) void denoise_kernel(
    const float* __restrict__ y, const float* __restrict__ xsrc,
    const int* __restrict__ idx, const float* __restrict__ sigma_p,
    float* __restrict__ acc) {
    constexpr int PADM = (M + 3) & ~3;  // 56 for M=55, 20 for M=18
    constexpr int PD = SBSTR;
    constexpr int TPK = M * (M + 1) / 2;
    constexpr int NS = (TPK + 255) / 256;
    constexpr int NCOL = M + NP;
    constexpr int CPW = (NCOL + 3) / 4;
    __shared__ __align__(16) float Ys[M][YSTR];
    __shared__ __align__(16) float SB[PADM * PD];  // R2: Xs rows -> later L
    __shared__ float cbuf[2][64];
    __shared__ float dvals[PADM];
    __shared__ float rdiag[PADM];
    __shared__ float wsh[M];
    __shared__ int gix[M];
    const int b = blockIdx.x, n = blockIdx.y;
    const int t = threadIdx.x;
    if (t < M) gix[t] = idx[(size_t)(n * NB + b) * M + t];
    __syncthreads();
    const float* im = y + (size_t)n * IMG_SZ;
    const float* xim = xsrc + (size_t)n * IMG_SZ;
    for (int e = t; e < M * YSTR; e += 256) {
        int i = e / YSTR, ch = e - i * YSTR;
        int p = gix[i];
        float v = 0.f, vx = 0.f;
        if (ch < NP) {
            int off = (p / HP + ch / 7) * IMG_W + (p % HP + ch % 7);
            v = im[off];
            if (R2) vx = xim[off];
        }
        Ys[i][ch] = v;
        if (R2) SB[i * PD + ch] = vx;  // cols [0,52); cols >=52 never read
    }
    __syncthreads();
    const float sg = sigma_p[0];
    const float cns = 49.f * sg * sg;
    // --- fixed slot ownership over packed lower triangle ---
    int siR[NS], sjR[NS];
    float gsum[NS];
#pragma unroll
    for (int s = 0; s < NS; ++s) {
        int e = t + 256 * s;
        if (e < TPK) {
            int i = (int)((sqrtf(8.f * e + 1.f) - 1.f) * 0.5f);
            while ((i + 1) * (i + 2) / 2 <= e) ++i;
            while (i * (i + 1) / 2 > e) --i;
            siR[s] = i;
            sjR[s] = e - i * (i + 1) / 2;
        } else {
            siR[s] = -1;
            sjR[s] = 0;
        }
    }
    // --- Gram into registers ---
#pragma unroll
    for (int s = 0; s < NS; ++s) {
        float sum = 0.f;
        if (siR[s] >= 0) {
            const float* Pi = R2 ? &SB[siR[s] * PD] : &Ys[siR[s]][0];
            const float* Pj = R2 ? &SB[sjR[s] * PD] : &Ys[sjR[s]][0];
#pragma unroll
            for (int q = 0; q < 13; ++q) {
                float4 a = *(const float4*)(Pi + 4 * q);
                float4 c4 = *(const float4*)(Pj + 4 * q);
                sum = fmaf(a.x, c4.x, sum);
                sum = fmaf(a.y, c4.y, sum);
                sum = fmaf(a.z, c4.z, sum);
                sum = fmaf(a.w, c4.w, sum);
            }
            if (R2 && siR[s] == sjR[s]) sum += cns;
        }
        gsum[s] = sum;
    }
    // --- init column 0, dvals[0]; identity-fill SB padding rows ---
#pragma unroll
    for (int s = 0; s < NS; ++s)
        if (siR[s] >= 0 && sjR[s] == 0) {
            cbuf[0][siR[s]] = gsum[s];
            if (siR[s] == 0) dvals[0] = gsum[s];
        }
    for (int e = t; e < (PADM - M) * PADM; e += 256) {
        int pr = M + e / PADM, pc = e % PADM;
        SB[pr * PD + pc] = (pr == pc) ? 1.f : 0.f;
    }
    __syncthreads();
    // --- Cholesky, d^2-form, trailing matrix in registers ---
#pragma unroll 1
    for (int k = 0; k < M - 1; ++k) {
        const float* cb = cbuf[k & 1];
        float* cn = cbuf[(k + 1) & 1];
        float ivd = 1.f / cb[k];
#pragma unroll
        for (int s = 0; s < NS; ++s) {
            if (siR[s] > k && sjR[s] > k) {
                float v = fmaf(-(cb[siR[s]] * ivd), cb[sjR[s]], gsum[s]);
                gsum[s] = v;
                if (sjR[s] == k + 1) {
                    cn[siR[s]] = v;
                    if (siR[s] == k + 1) dvals[k + 1] = v;
                }
            }
        }
        __syncthreads();
    }
    if (t < PADM) rdiag[t] = (t < M) ? 1.f / sqrtf(dvals[t]) : 1.f;
    __syncthreads();
    // --- write L = raw * rdiag[col] into SB (single pass) ---
#pragma unroll
    for (int s = 0; s < NS; ++s)
        if (siR[s] >= 0) SB[siR[s] * PD + sjR[s]] = gsum[s] * rdiag[sjR[s]];
    __syncthreads();
    // --- solves: 104 columns spread 26 per wave (id cols -> weights, Y cols -> X_hat) ---
    const int lane = t & 63, wv = t >> 6;
    const int c = wv * CPW + lane;
    const bool act = (lane < CPW) && (c < NCOL);
    const bool isId = act && (c < M);
    const bool isY = act && (c >= M);
    const int ch = isY ? (c - M) : 0;
    float bb[PADM];
    if (isY) {
#pragma unroll
        for (int i = 0; i < PADM; ++i) bb[i] = (i < M) ? Ys[i][ch] : 0.f;
    } else {
#pragma unroll
        for (int i = 0; i < PADM; ++i) bb[i] = (i == c) ? 1.f : 0.f;
    }
    // forward: L z = b, 4-wide chunks; all L loads wave-uniform broadcasts
#pragma unroll
    for (int ck = 0; ck < PADM / 4; ++ck) {
        const int i0 = 4 * ck;
        float L10 = SB[(i0 + 1) * PD + i0];
        float L20 = SB[(i0 + 2) * PD + i0], L21 = SB[(i0 + 2) * PD + i0 + 1];
        float L30 = SB[(i0 + 3) * PD + i0], L31 = SB[(i0 + 3) * PD + i0 + 1],
              L32 = SB[(i0 + 3) * PD + i0 + 2];
        float b0 = bb[i0] * rdiag[i0];
        float b1 = (bb[i0 + 1] - L10 * b0) * rdiag[i0 + 1];
        float b2 = (bb[i0 + 2] - L20 * b0 - L21 * b1) * rdiag[i0 + 2];
        float b3 = (bb[i0 + 3] - L30 * b0 - L31 * b1 - L32 * b2) * rdiag[i0 + 3];
        bb[i0] = b0; bb[i0 + 1] = b1; bb[i0 + 2] = b2; bb[i0 + 3] = b3;
#pragma unroll
        for (int j = i0 + 4; j < PADM; ++j) {
            float4 L4 = *(const float4*)&SB[j * PD + i0];
            bb[j] = fmaf(-L4.x, b0, fmaf(-L4.y, b1, fmaf(-L4.z, b2, fmaf(-L4.w, b3, bb[j]))));
        }
        asm volatile("" ::: "memory");  // cap load hoisting across chunks
    }
    // backward: L^T x = z, row sweeps as aligned float4 + compile-time tails
#pragma unroll
    for (int i = PADM - 1; i >= 0; --i) {
        float bbi = bb[i] * rdiag[i];
        bb[i] = bbi;
#pragma unroll
        for (int qb = 0; qb < i / 4; ++qb) {
            float4 L4 = *(const float4*)&SB[i * PD + 4 * qb];
            bb[4 * qb + 0] = fmaf(-L4.x, bbi, bb[4 * qb + 0]);
            bb[4 * qb + 1] = fmaf(-L4.y, bbi, bb[4 * qb + 1]);
            bb[4 * qb + 2] = fmaf(-L4.z, bbi, bb[4 * qb + 2]);
            bb[4 * qb + 3] = fmaf(-L4.w, bbi, bb[4 * qb + 3]);
        }
#pragma unroll
        for (int j = i & ~3; j < i; ++j)
            bb[j] = fmaf(-SB[i * PD + j], bbi, bb[j]);
        if ((i & 3) == 0) asm volatile("" ::: "memory");
    }
    // --- epilogue: weights (theta symmetric), X_hat in place, fused scatter ---
    if (isId) {
        float s2 = 0.f;
#pragma unroll
        for (int i = 0; i < M; ++i) {
            float th = ((i == c) ? 1.f : 0.f) - cns * bb[i];
            s2 = fmaf(th, th, s2);
        }
        s2 = fminf(fmaxf(s2, 1.f / (float)M), 1.f);
        wsh[c] = 1.f / s2;
    }
    if (isY) {
#pragma unroll
        for (int i = 0; i < M; ++i) Ys[i][ch] = fmaf(-cns, bb[i], Ys[i][ch]);
    }
    __syncthreads();
    float* aA = acc + (size_t)n * IMG_SZ * 2;
    for (int e = t; e < M * NP; e += 256) {
        int i = e / NP, c2 = e % NP;
        int p = gix[i];
        int pix = (p / HP + c2 / 7) * IMG_W + (p % HP + c2 % 7);
        float wi = wsh[i];
        atomicAdd(&aA[pix * 2], Ys[i][c2] * wi);
        atomicAdd(&aA[pix * 2 + 1], wi);
    }
}

extern "C" void kernel_launch(void* const* d_in, const int* in_sizes, int n_in,
                              void* d_out, int out_size, void* d_ws, size_t ws_size,
                              hipStream_t stream) {
    const float* y = (const float*)d_in[0];
    const float* sigma = (const float*)d_in[1];
    float* out = (float*)d_out;

    char* ws = (char*)d_ws;
    size_t off = 0;
    auto carve = [&](size_t bytes) {
        void* p = ws + off;
        off += (bytes + 255) & ~(size_t)255;
        return p;
    };
    int* idx1 = (int*)carve((size_t)NIMG * NB * 18 * sizeof(int));
    int* idx2 = (int*)carve((size_t)NIMG * NB * 55 * sizeof(int));
    float* acc = (float*)carve((size_t)NIMG * IMG_SZ * 2 * sizeof(float));
    float* den1 = (float*)carve((size_t)NIMG * IMG_SZ * sizeof(float));

    const int accTotal = NIMG * IMG_SZ * 2;
    const int imgTotal = NIMG * IMG_SZ;

    // Round 1: M1=18
    zero_kernel<<<(accTotal + 255) / 256, 256, 0, stream>>>(acc, accTotal);
    bm_kernel<18><<<dim3(16, 64, NIMG), 256, 0, stream>>>(y, idx1);
    denoise_kernel<18, false><<<dim3(NB, NIMG), 256, 0, stream>>>(y, y, idx1, sigma, acc);
    div_kernel<<<(imgTotal + 255) / 256, 256, 0, stream>>>(acc, den1, imgTotal);

    // Round 2: M2=55
    zero_kernel<<<(accTotal + 255) / 256, 256, 0, stream>>>(acc, accTotal);
    bm_kernel<55><<<dim3(16, 64, NIMG), 256, 0, stream>>>(den1, idx2);
    denoise_kernel<55, true><<<dim3(NB, NIMG), 256, 0, stream>>>(y, den1, idx2, sigma, acc);
    div_kernel<<<(imgTotal + 255) / 256, 256, 0, stream>>>(acc, out, imgTotal);
}

// Round 6
// 1359.119 us; speedup vs baseline: 3.5542x; 1.0684x over previous
//
#include <hip/hip_runtime.h>
#include <math.h>

#define IMG_H 256
#define IMG_W 256
#define IMG_SZ (IMG_H * IMG_W)
#define NP 49      /* C*p*p patch vector length */
#define HP 250     /* H - p + 1 */
#define NB 4096    /* groups per image = 64*64 */
#define NCAND 1369 /* 37*37 */
#define VRAD 18
#define CENTER (VRAD * 37 + VRAD)
#define NIMG 2
#define YSTR 52    /* Ys row stride: 208B, 16B aligned */
#define WSTR 55    /* bm window stride: odd -> conflict-free */

// Map aligned-patch coordinates (253x253, after align_corners with s=4 on a
// 250x250 grid) to original patch coordinates. Returns false for inf slots.
__device__ __forceinline__ bool align_map(int r, int c, int& ro, int& co) {
    if (r < 0 || r > 252 || c < 0 || c > 252) return false;
    if (r == 252) {
        if (c == 252) { ro = 249; co = 249; return true; }
        if (c <= 248 && (c & 3) == 0) { ro = 249; co = c; return true; }
        return false;
    }
    if (c == 252) {
        if (r <= 248 && (r & 3) == 0) { ro = r; co = 249; return true; }
        return false;
    }
    if (r >= 250 || c >= 250) return false;
    if (r == 249) {
        if (c == 249) return false;
        if ((c & 3) == 0) return false;
        ro = 249; co = c; return true;
    }
    if (c == 249) {
        if ((r & 3) == 0) return false;
        ro = r; co = 249; return true;
    }
    ro = r; co = c; return true;
}

__global__ void zero_kernel(float* __restrict__ p, int total) {
    int i = blockIdx.x * blockDim.x + threadIdx.x;
    if (i < total) p[i] = 0.0f;
}

// acc holds interleaved (num, weight) pairs per pixel.
__global__ void div_kernel(const float* __restrict__ acc, float* __restrict__ out, int total) {
    int i = blockIdx.x * blockDim.x + threadIdx.x;
    if (i < total) out[i] = acc[2 * i] / acc[2 * i + 1];
}

// 4 reference patches per 256-thread block (one wave each), sharing one staged
// union window. refp in registers; center forced during fill; selection via
// barrier-free shfl butterfly over per-lane top-2 caches.
template <int M>
__global__ __launch_bounds__(256) void bm_kernel(const float* __restrict__ img,
                                                 int* __restrict__ idx_out) {
    __shared__ float win[43 * WSTR];
    __shared__ float dist[4][NCAND];
    const int llb = blockIdx.x, kk = blockIdx.y, n = blockIdx.z;
    const float* im = img + (size_t)n * IMG_SZ;
    const int t = threadIdx.x;
    const int w = t >> 6, lane = t & 63;
    const int ll = 4 * llb + w;
    const int rr = (kk < 63) ? 4 * kk : 249;
    const int cc = (ll < 63) ? 4 * ll : 249;
    const int ar0 = 4 * kk, ac0 = 4 * ll;
    const int acb = 16 * llb;
    const int row0 = max(0, ar0 - VRAD), col0 = max(0, acb - VRAD);
    const int row1 = min(IMG_H - 1, ar0 + VRAD + 6);
    const int col1 = min(IMG_W - 1, acb + 12 + VRAD + 6);
    const int nr = row1 - row0 + 1, nc = col1 - col0 + 1;
    for (int e = t; e < nr * nc; e += 256) {
        int r = e / nc, c = e % nc;
        win[r * WSTR + c] = im[(row0 + r) * IMG_W + col0 + c];
    }
    __syncthreads();
    float rf[NP];
    {
        const float* rb = &win[(rr - row0) * WSTR + (cc - col0)];
#pragma unroll
        for (int ki = 0; ki < 7; ++ki)
#pragma unroll
            for (int kj = 0; kj < 7; ++kj) rf[ki * 7 + kj] = rb[ki * WSTR + kj];
    }
    float* dw = dist[w];
    for (int cand = lane; cand < NCAND; cand += 64) {
        const int dr = cand / 37 - VRAD, dc = cand % 37 - VRAD;
        int ro, co;
        float d;
        if (align_map(ar0 + dr, ac0 + dc, ro, co)) {
            const float* base = &win[(ro - row0) * WSTR + (co - col0)];
            float s = 0.f;
#pragma unroll
            for (int ki = 0; ki < 7; ++ki)
#pragma unroll
                for (int kj = 0; kj < 7; ++kj) {
                    float df = base[ki * WSTR + kj] - rf[ki * 7 + kj] + 1e-6f;
                    s = fmaf(df, df, s);
                }
            d = sqrtf(s);
        } else {
            d = INFINITY;
        }
        if (cand == CENTER) d = -1.0f;  // center always wins sel 0
        dw[cand] = d;
    }
    __syncthreads();
    // per-lane top-2 over the strided bucket (ascending scan => ties keep low idx)
    float v1 = INFINITY, v2 = INFINITY;
    int i1 = NCAND, i2 = NCAND;
    for (int c = lane; c < NCAND; c += 64) {
        float v = dw[c];
        if (v < v1) { v2 = v1; i2 = i1; v1 = v; i1 = c; }
        else if (v < v2) { v2 = v; i2 = c; }
    }
    int* out = idx_out + (size_t)((n * 64 + kk) * 64 + ll) * M;
    for (int sel = 0; sel < M; ++sel) {
        float gv = v1;
        int gi = i1;
#pragma unroll
        for (int off = 32; off; off >>= 1) {
            float vv = __shfl_xor(gv, off);
            int ii = __shfl_xor(gi, off);
            if (vv < gv || (vv == gv && ii < gi)) { gv = vv; gi = ii; }
        }
        if (lane == 0) {
            int dr = gi / 37 - VRAD, dc = gi % 37 - VRAD;
            out[sel] = min(rr + dr, 249) * HP + min(cc + dc, 249);
        }
        if ((gi & 63) == lane) {  // owner pops its cache; rescan only if exhausted
            dw[gi] = INFINITY;
            v1 = v2; i1 = i2; v2 = INFINITY; i2 = NCAND;
            if (i1 == NCAND) {
                for (int c = lane; c < NCAND; c += 64) {
                    float v = dw[c];
                    if (v < v1) { v2 = v1; i2 = i1; v1 = v; i1 = c; }
                    else if (v < v2) { v2 = v; i2 = c; }
                }
            }
        }
    }
}

// 128 threads (2 waves) per group. theta = I - c*A^-1 in BOTH rounds.
// Gram: slot-distributed (both waves) -> SB triangle. Cholesky: wave0 only,
// rows in REGISTERS, zero barriers — per column one contiguous ds_write + a
// few uniform float4 broadcast reads; unconditional updates (symmetric full
// rows; mirror slots are benign garbage). L written once. Solve: wave0 = M
// identity cols (weights), wave1 = 49 Y cols (X_hat); uniform float4 L reads.
template <int M, bool R2>
__global__ __launch_bounds__(128, 2) void denoise_kernel(
    const float* __restrict__ y, const float* __restrict__ xsrc,
    const int* __restrict__ idx, const float* __restrict__ sigma_p,
    float* __restrict__ acc) {
    constexpr int PADM = (M + 3) & ~3;  // 56 for M=55, 20 for M=18
    constexpr int PD = PADM + 4;        // 60 / 24: row stride in floats
    constexpr int TPK = M * (M + 1) / 2;
    constexpr int NS = (TPK + 127) / 128;
    constexpr int NCH = PADM / 4;
    __shared__ __align__(16) float Ys[M][YSTR];
    __shared__ __align__(16) float SB[PADM * PD];  // R2: Xs rows -> A -> L
    __shared__ float cbuf[64];
    __shared__ __align__(16) float rdiag[PADM];
    __shared__ float wsh[M];
    __shared__ int gix[M];
    const int b = blockIdx.x, n = blockIdx.y;
    const int t = threadIdx.x;
    const int lane = t & 63, wv = t >> 6;
    if (t < M) gix[t] = idx[(size_t)(n * NB + b) * M + t];
    __syncthreads();
    const float* im = y + (size_t)n * IMG_SZ;
    const float* xim = xsrc + (size_t)n * IMG_SZ;
    for (int e = t; e < M * YSTR; e += 128) {
        int i = e / YSTR, ch = e - i * YSTR;
        int p = gix[i];
        float v = 0.f, vx = 0.f;
        if (ch < NP) {
            int off = (p / HP + ch / 7) * IMG_W + (p % HP + ch % 7);
            v = im[off];
            if (R2) vx = xim[off];
        }
        Ys[i][ch] = v;
        if (R2) SB[i * PD + ch] = vx;  // cols [0,52); zero-padded 49..51
    }
    __syncthreads();
    const float sg = sigma_p[0];
    const float cns = 49.f * sg * sg;
    // --- Gram, slot-distributed over 128 threads, results in registers ---
    int siR[NS], sjR[NS];
    float gsum[NS];
#pragma unroll
    for (int s = 0; s < NS; ++s) {
        int e = t + 128 * s;
        if (e < TPK) {
            int i = (int)((sqrtf(8.f * e + 1.f) - 1.f) * 0.5f);
            while ((i + 1) * (i + 2) / 2 <= e) ++i;
            while (i * (i + 1) / 2 > e) --i;
            siR[s] = i;
            sjR[s] = e - i * (i + 1) / 2;
        } else {
            siR[s] = -1;
            sjR[s] = 0;
        }
    }
#pragma unroll
    for (int s = 0; s < NS; ++s) {
        float sum = 0.f;
        if (siR[s] >= 0) {
            const float* Pi = R2 ? &SB[siR[s] * PD] : &Ys[siR[s]][0];
            const float* Pj = R2 ? &SB[sjR[s] * PD] : &Ys[sjR[s]][0];
#pragma unroll
            for (int q = 0; q < 13; ++q) {
                float4 a = *(const float4*)(Pi + 4 * q);
                float4 c4 = *(const float4*)(Pj + 4 * q);
                sum = fmaf(a.x, c4.x, sum);
                sum = fmaf(a.y, c4.y, sum);
                sum = fmaf(a.z, c4.z, sum);
                sum = fmaf(a.w, c4.w, sum);
            }
            if (R2 && siR[s] == sjR[s]) sum += cns;
        }
        gsum[s] = sum;
    }
    __syncthreads();  // all Gram reads of SB done before overlay
#pragma unroll
    for (int s = 0; s < NS; ++s)
        if (siR[s] >= 0) {
            SB[siR[s] * PD + sjR[s]] = gsum[s];
            SB[sjR[s] * PD + siR[s]] = gsum[s];  // mirror: full symmetric rows
        }
    __syncthreads();
    // --- wave0: register-row Cholesky (d^2 form), zero barriers ---
    if (wv == 0) {
        float g[PADM];
        const int ri = (lane < M) ? lane : 0;
#pragma unroll
        for (int jb = 0; jb < NCH; ++jb) {
            float4 v4 = *(const float4*)&SB[ri * PD + 4 * jb];
            g[4 * jb] = v4.x; g[4 * jb + 1] = v4.y; g[4 * jb + 2] = v4.z; g[4 * jb + 3] = v4.w;
        }
        if (lane >= M) {
#pragma unroll
            for (int j = 0; j < PADM; ++j) g[j] = (j == lane) ? 1.f : 0.f;
        }
#pragma unroll
        for (int k = 0; k < PADM - 1; ++k) {
            cbuf[lane] = g[k];
            float ivd = 1.f / cbuf[k];
            float fk = g[k] * ivd;
#pragma unroll
            for (int jb = (k + 1) / 4; jb < NCH; ++jb) {
                float4 cv = *(const float4*)&cbuf[4 * jb];
                if (4 * jb + 0 > k) g[4 * jb + 0] = fmaf(-fk, cv.x, g[4 * jb + 0]);
                if (4 * jb + 1 > k) g[4 * jb + 1] = fmaf(-fk, cv.y, g[4 * jb + 1]);
                if (4 * jb + 2 > k) g[4 * jb + 2] = fmaf(-fk, cv.z, g[4 * jb + 2]);
                if (4 * jb + 3 > k) g[4 * jb + 3] = fmaf(-fk, cv.w, g[4 * jb + 3]);
            }
        }
        if (lane < PADM) rdiag[lane] = (lane < M) ? 1.f / sqrtf(g[lane]) : 1.f;
        // scale row by rdiag[col] and store L (only j<=i ever read by solves)
        if (lane < PADM) {
#pragma unroll
            for (int jb = 0; jb < NCH; ++jb) {
                float4 rd = *(const float4*)&rdiag[4 * jb];
                float4 o;
                o.x = g[4 * jb] * rd.x; o.y = g[4 * jb + 1] * rd.y;
                o.z = g[4 * jb + 2] * rd.z; o.w = g[4 * jb + 3] * rd.w;
                *(float4*)&SB[lane * PD + 4 * jb] = o;
            }
        }
    }
    __syncthreads();
    // --- solves: wave0 lane -> identity col (weights), wave1 lane -> Y col ---
    const bool isId = (wv == 0) && (lane < M);
    const bool isY = (wv == 1) && (lane < NP);
    const int ch = (wv == 1 && lane < NP) ? lane : 0;
    float bb[PADM];
    if (wv == 1) {
#pragma unroll
        for (int i = 0; i < PADM; ++i) bb[i] = (i < M) ? Ys[i][ch] : 0.f;
    } else {
#pragma unroll
        for (int i = 0; i < PADM; ++i) bb[i] = (i == lane) ? 1.f : 0.f;
    }
    // forward: L z = b, 4-wide chunks; all L loads wave-uniform broadcasts
#pragma unroll
    for (int ck = 0; ck < NCH; ++ck) {
        const int i0 = 4 * ck;
        float L10 = SB[(i0 + 1) * PD + i0];
        float L20 = SB[(i0 + 2) * PD + i0], L21 = SB[(i0 + 2) * PD + i0 + 1];
        float L30 = SB[(i0 + 3) * PD + i0], L31 = SB[(i0 + 3) * PD + i0 + 1],
              L32 = SB[(i0 + 3) * PD + i0 + 2];
        float b0 = bb[i0] * rdiag[i0];
        float b1 = (bb[i0 + 1] - L10 * b0) * rdiag[i0 + 1];
        float b2 = (bb[i0 + 2] - L20 * b0 - L21 * b1) * rdiag[i0 + 2];
        float b3 = (bb[i0 + 3] - L30 * b0 - L31 * b1 - L32 * b2) * rdiag[i0 + 3];
        bb[i0] = b0; bb[i0 + 1] = b1; bb[i0 + 2] = b2; bb[i0 + 3] = b3;
#pragma unroll
        for (int j = i0 + 4; j < PADM; ++j) {
            float4 L4 = *(const float4*)&SB[j * PD + i0];
            bb[j] = fmaf(-L4.x, b0, fmaf(-L4.y, b1, fmaf(-L4.z, b2, fmaf(-L4.w, b3, bb[j]))));
        }
        asm volatile("" ::: "memory");  // cap load hoisting across chunks
    }
    // backward: L^T x = z, row sweeps as aligned float4 + compile-time tails
#pragma unroll
    for (int i = PADM - 1; i >= 0; --i) {
        float bbi = bb[i] * rdiag[i];
        bb[i] = bbi;
#pragma unroll
        for (int qb = 0; qb < i / 4; ++qb) {
            float4 L4 = *(const float4*)&SB[i * PD + 4 * qb];
            bb[4 * qb + 0] = fmaf(-L4.x, bbi, bb[4 * qb + 0]);
            bb[4 * qb + 1] = fmaf(-L4.y, bbi, bb[4 * qb + 1]);
            bb[4 * qb + 2] = fmaf(-L4.z, bbi, bb[4 * qb + 2]);
            bb[4 * qb + 3] = fmaf(-L4.w, bbi, bb[4 * qb + 3]);
        }
#pragma unroll
        for (int j = i & ~3; j < i; ++j)
            bb[j] = fmaf(-SB[i * PD + j], bbi, bb[j]);
        if ((i & 3) == 0) asm volatile("" ::: "memory");
    }
    // --- epilogue: weights (theta symmetric), X_hat in place, fused scatter ---
    if (isId) {
        float s2 = 0.f;
#pragma unroll
        for (int i = 0; i < M; ++i) {
            float th = ((i == lane) ? 1.f : 0.f) - cns * bb[i];
            s2 = fmaf(th, th, s2);
        }
        s2 = fminf(fmaxf(s2, 1.f / (float)M), 1.f);
        wsh[lane] = 1.f / s2;
    }
    if (isY) {
#pragma unroll
        for (int i = 0; i < M; ++i) Ys[i][ch] = fmaf(-cns, bb[i], Ys[i][ch]);
    }
    __syncthreads();
    float* aA = acc + (size_t)n * IMG_SZ * 2;
    for (int e = t; e < M * NP; e += 128) {
        int i = e / NP, c2 = e % NP;
        int p = gix[i];
        int pix = (p / HP + c2 / 7) * IMG_W + (p % HP + c2 % 7);
        float wi = wsh[i];
        atomicAdd(&aA[pix * 2], Ys[i][c2] * wi);
        atomicAdd(&aA[pix * 2 + 1], wi);
    }
}

extern "C" void kernel_launch(void* const* d_in, const int* in_sizes, int n_in,
                              void* d_out, int out_size, void* d_ws, size_t ws_size,
                              hipStream_t stream) {
    const float* y = (const float*)d_in[0];
    const float* sigma = (const float*)d_in[1];
    float* out = (float*)d_out;

    char* ws = (char*)d_ws;
    size_t off = 0;
    auto carve = [&](size_t bytes) {
        void* p = ws + off;
        off += (bytes + 255) & ~(size_t)255;
        return p;
    };
    int* idx1 = (int*)carve((size_t)NIMG * NB * 18 * sizeof(int));
    int* idx2 = (int*)carve((size_t)NIMG * NB * 55 * sizeof(int));
    float* acc = (float*)carve((size_t)NIMG * IMG_SZ * 2 * sizeof(float));
    float* den1 = (float*)carve((size_t)NIMG * IMG_SZ * sizeof(float));

    const int accTotal = NIMG * IMG_SZ * 2;
    const int imgTotal = NIMG * IMG_SZ;

    // Round 1: M1=18
    zero_kernel<<<(accTotal + 255) / 256, 256, 0, stream>>>(acc, accTotal);
    bm_kernel<18><<<dim3(16, 64, NIMG), 256, 0, stream>>>(y, idx1);
    denoise_kernel<18, false><<<dim3(NB, NIMG), 128, 0, stream>>>(y, y, idx1, sigma, acc);
    div_kernel<<<(imgTotal + 255) / 256, 256, 0, stream>>>(acc, den1, imgTotal);

    // Round 2: M2=55
    zero_kernel<<<(accTotal + 255) / 256, 256, 0, stream>>>(acc, accTotal);
    bm_kernel<55><<<dim3(16, 64, NIMG), 256, 0, stream>>>(den1, idx2);
    denoise_kernel<55, true><<<dim3(NB, NIMG), 128, 0, stream>>>(y, den1, idx2, sigma, acc);
    div_kernel<<<(imgTotal + 255) / 256, 256, 0, stream>>>(acc, out, imgTotal);
}